// Round 12
// baseline (275.398 us; speedup 1.0000x reference)
//
#include <hip/hip_runtime.h>
#include <hip/hip_bf16.h>

#define EPS 1e-5f

typedef __attribute__((ext_vector_type(8))) short bf16x8;
typedef __attribute__((ext_vector_type(4))) short bf16x4;
typedef __attribute__((ext_vector_type(4))) float f32x4;

__device__ __forceinline__ f32x4 mfma_bf16(bf16x8 a, bf16x8 b, f32x4 c) {
    return __builtin_amdgcn_mfma_f32_16x16x32_bf16(a, b, c, 0, 0, 0);
}

__device__ __forceinline__ void async_ld16(const void* g, void* l) {
    __builtin_amdgcn_global_load_lds(
        (const __attribute__((address_space(1))) void*)g,
        (__attribute__((address_space(3))) void*)l, 16, 0, 0);
}

// fast gelu: 0.5v(1+tanh z) == v * sigmoid(2z); one v_exp + one rcp.
__device__ __forceinline__ float fast_gelu(float v) {
    float z2 = 1.5957691216057308f * (v + 0.044715f * v * v * v);
    float e = __expf(z2);
    return v * e / (e + 1.f);
}

__device__ __forceinline__ float bf2f(short s) {
    union { float f; unsigned u; } v;
    v.u = ((unsigned)(unsigned short)s) << 16;
    return v.f;
}

__device__ __forceinline__ short f2bf_s(float x) {
    union { __hip_bfloat16 h; short s; } cv;
    cv.h = __float2bfloat16(x);
    return cv.s;
}

// 8-wide f32 -> bf16 convert (32B read, 16B write)
__device__ __forceinline__ void cvt8(const float* __restrict__ src,
                                     __hip_bfloat16* __restrict__ dst) {
    float4 v0 = *(const float4*)src;
    float4 v1 = *(const float4*)(src + 4);
    bf16x8 r;
    r[0] = f2bf_s(v0.x); r[1] = f2bf_s(v0.y); r[2] = f2bf_s(v0.z); r[3] = f2bf_s(v0.w);
    r[4] = f2bf_s(v1.x); r[5] = f2bf_s(v1.y); r[6] = f2bf_s(v1.z); r[7] = f2bf_s(v1.w);
    *(bf16x8*)dst = r;
}

// ---------------- merged pre-work: f32->bf16 weight convert (blocks 0..3455,
// 8 elems/thread, vectorized: R23 dispatch-overhead fix, was 27648 scalar
// blocks) + adaLN mods[b][i] = c[b].adaLN_w[i] + adaLN_b[i] (last 36 blocks)
__global__ void k_pre(const float* __restrict__ a, __hip_bfloat16* __restrict__ oa, int na,
                      const float* __restrict__ b, __hip_bfloat16* __restrict__ ob, int nb,
                      const float* __restrict__ c, __hip_bfloat16* __restrict__ oc, int nc,
                      const float* __restrict__ d, __hip_bfloat16* __restrict__ od, int nd,
                      const float* __restrict__ cond, const float* __restrict__ alw,
                      const float* __restrict__ alb, float* __restrict__ mods) {
    if (blockIdx.x >= 3456) {
        int i = (blockIdx.x - 3456) * 256 + threadIdx.x;   // 0..9215
        int bb = i / 4608, row = i - bb * 4608;
        const float4* cv = (const float4*)(cond + bb * 128);
        const float4* wv = (const float4*)(alw + (long)row * 128);
        float acc = 0.f;
#pragma unroll
        for (int k = 0; k < 32; ++k) {
            float4 x = cv[k], y = wv[k];
            acc += x.x * y.x + x.y * y.y + x.z * y.z + x.w * y.w;
        }
        mods[i] = acc + alb[row];
        return;
    }
    long i = ((long)blockIdx.x * 256 + threadIdx.x) * 8;   // all sizes %8==0
    if (i < na) { cvt8(a + i, oa + i); return; }
    i -= na;
    if (i < nb) { cvt8(b + i, ob + i); return; }
    i -= nb;
    if (i < nc) { cvt8(c + i, oc + i); return; }
    i -= nc;
    if (i < nd) cvt8(d + i, od + i);
}

// ---------------- fused LayerNorm + adaLN modulate, 1 wave per token,
// 4 tokens per 256-thread block (R23: was 4096 blocks x 64 threads).
__global__ __launch_bounds__(256) void k_ln_mod(
        const float* __restrict__ x, const float* __restrict__ w,
        const float* __restrict__ mods, int shiftOff, int scaleOff,
        __hip_bfloat16* __restrict__ out) {
    int token = blockIdx.x * 4 + (threadIdx.x >> 6);    // 0..4095
    int lane = threadIdx.x & 63;
    const float4* xr = (const float4*)(x + (long)token * 768);
    float4 v0 = xr[lane], v1 = xr[lane + 64], v2 = xr[lane + 128];
    float s  = v0.x + v0.y + v0.z + v0.w + v1.x + v1.y + v1.z + v1.w + v2.x + v2.y + v2.z + v2.w;
    float ss = v0.x*v0.x + v0.y*v0.y + v0.z*v0.z + v0.w*v0.w
             + v1.x*v1.x + v1.y*v1.y + v1.z*v1.z + v1.w*v1.w
             + v2.x*v2.x + v2.y*v2.y + v2.z*v2.z + v2.w*v2.w;
#pragma unroll
    for (int m = 32; m >= 1; m >>= 1) { s += __shfl_xor(s, m); ss += __shfl_xor(ss, m); }
    float mu = s * (1.f / 768.f);
    float var = ss * (1.f / 768.f) - mu * mu;
    float rs = rsqrtf(var + EPS);
    int b = token >> 11;
    const float* sh = mods + b * 4608 + shiftOff;
    const float* sc = mods + b * 4608 + scaleOff;
    __hip_bfloat16* o = out + (long)token * 768;
    float4 vv[3] = {v0, v1, v2};
#pragma unroll
    for (int kk = 0; kk < 3; ++kk) {
        int cbase = (lane + 64 * kk) * 4;
        const float* p = (const float*)&vv[kk];
#pragma unroll
        for (int j = 0; j < 4; ++j) {
            int col = cbase + j;
            float hv = (p[j] - mu) * rs * w[col] * (1.f + sc[col]) + sh[col];
            o[col] = __float2bfloat16(hv);
        }
    }
}

// ---------------- split-K reduce + mlp2 epilogue (4 partials), grid-stride
// (R23: 1536 blocks): out = x2 + gate*(p0+p1+p2+p3 + bias).
__global__ __launch_bounds__(256) void k_red(
        const __hip_bfloat16* __restrict__ p, const float* __restrict__ x2,
        const float* __restrict__ mods, const float* __restrict__ bias,
        float* __restrict__ out) {
    for (long tt = (long)blockIdx.x * 256 + threadIdx.x; tt < 786432;
         tt += (long)gridDim.x * 256) {
        long base = tt * 4;
        int col = (int)(base % 768);
        int row = (int)(base / 768);
        int b = row >> 11;
        float sx = 0.f, sy = 0.f, sz = 0.f, sw = 0.f;
#pragma unroll
        for (int z = 0; z < 4; ++z) {
            short4 a = *(const short4*)(p + (long)z * 3145728 + base);
            sx += bf2f(a.x); sy += bf2f(a.y); sz += bf2f(a.z); sw += bf2f(a.w);
        }
        float4 xr = *(const float4*)(x2 + base);
        float4 gt = *(const float4*)(mods + b * 4608 + 3840 + col);
        float4 bs = *(const float4*)(bias + col);
        float4 o;
        o.x = xr.x + gt.x * (sx + bs.x);
        o.y = xr.y + gt.y * (sy + bs.y);
        o.z = xr.z + gt.z * (sz + bs.z);
        o.w = xr.w + gt.w * (sw + bs.w);
        *(float4*)(out + base) = o;
    }
}

// ---------------- block-sparse flash attention, no-max softmax.
// R18: coalesced LDS staging of K/V (shared across 4 waves/workgroup) cut
// scattered-gather txns ~10x -> 56 -> ~36us. R19 deferred-PV pipeline:
// neutral (kept). Structure: workgroup = 4 q-blocks sharing a prefix,
// w=0..3 <-> (fl,blk) in {(0,b0),(1,b0),(0,b0+1),(1,b0+1)}; K/V chunks
// staged via coalesced global_load_lds (dbuf, vmcnt(4)), XOR-swizzled via
// pre-swizzled GLOBAL source (LDS dest linear, m104/m173); conflict-free
// ds_read_b128 fragments. Per-wave act masks; tail subtiles masked p=0.
__global__ __launch_bounds__(256) void k_attn(
    const __hip_bfloat16* __restrict__ q, const __hip_bfloat16* __restrict__ k,
    const __hip_bfloat16* __restrict__ vT, __hip_bfloat16* __restrict__ out) {
    __shared__ __hip_bfloat16 KL[2][64 * 64];   // [buf][key(64)][dim(64)] swizzled
    __shared__ __hip_bfloat16 VL[2][64 * 64];   // [buf][dim(64)][lkey(64)] swizzled
    __shared__ __hip_bfloat16 P[4][16 * 68];    // per-wave P tile
    int tid = threadIdx.x;
    int w = tid >> 6, lane = tid & 63, l15 = lane & 15, quad = lane >> 4;
    int idx = blockIdx.x;                  // 0..767
    int bh = idx % 24;                     // fastest: spreads across XCDs
    int gi = idx / 24;                     // 0..31
    int b0 = 62 - 2 * gi;                  // longest prefix first
    int fl = w & 1, blk = b0 + (w >> 1);
    int qblk = fl * 64 + blk;

    const __hip_bfloat16* Q = q + ((long)bh * 2048 + qblk * 16) * 64;
    bf16x8 qa = *(const bf16x8*)(Q + l15 * 64 + quad * 8);
    bf16x8 qb = *(const bf16x8*)(Q + l15 * 64 + 32 + quad * 8);
    const __hip_bfloat16* K = k + (long)bh * 2048 * 64;
    const __hip_bfloat16* V = vT + (long)bh * 64 * 2048;

    // staged subtile t -> global key base (clamped to 0 when out of range)
    auto kbase = [&](int t) -> int {
        if (t < b0 + 2) return 1024 + t * 16;
        if (t == b0 + 2) return b0 * 16;
        if (t == b0 + 3) return (b0 + 1) * 16;
        return 0;
    };
    // per-wave subtile activity (wave-uniform)
    auto active = [&](int t) -> bool {
        if (w == 0) return t < b0 || t == b0 + 2;
        if (w == 1) return t < b0 + 1;
        if (w == 2) return t < b0 + 1 || t == b0 + 3;
        return t < b0 + 2;
    };

    // staging decode constants (per thread: 2 K instrs + 2 V instrs)
    int kkr[2], kbs[2], vsi[2], vki[2];
#pragma unroll
    for (int i = 0; i < 2; ++i) {
        int o = i * 4096 + tid * 16;
        kkr[i] = o >> 7;
        int b = o & 127;
        kbs[i] = b ^ ((kkr[i] & 7) << 4);
        int lk2 = b ^ ((kkr[i] & 7) << 4);   // same row index for V decode
        vsi[i] = lk2 >> 5;
        vki[i] = (lk2 & 31) >> 1;
    }
    auto stage = [&](int ci, int buf) {
#pragma unroll
        for (int i = 0; i < 2; ++i) {
            int gk = kbase(4 * ci + (kkr[i] >> 4)) + (kkr[i] & 15);
            async_ld16(K + (long)gk * 64 + (kbs[i] >> 1),
                       (char*)&KL[buf][0] + i * 4096 + tid * 16);
        }
#pragma unroll
        for (int i = 0; i < 2; ++i) {
            int gk = kbase(4 * ci + vsi[i]) + vki[i];
            async_ld16(V + (long)kkr[i] * 2048 + gk,
                       (char*)&VL[buf][0] + i * 4096 + tid * 16);
        }
    };

    // fragment LDS offsets (shorts), swizzle matches staging
    int kfo[4][2], vfo[2][4];
#pragma unroll
    for (int s = 0; s < 4; ++s)
#pragma unroll
        for (int h = 0; h < 2; ++h)
            kfo[s][h] = (s * 16 + l15) * 64 +
                        (((h * 64 + quad * 16) ^ ((l15 & 7) << 4)) >> 1);
#pragma unroll
    for (int p2 = 0; p2 < 2; ++p2)
#pragma unroll
        for (int tt = 0; tt < 4; ++tt) {
            int d = tt * 16 + l15;
            int c = (p2 * 64 + (quad >> 1) * 32 + (quad & 1) * 16) ^ ((l15 & 7) << 4);
            vfo[p2][tt] = d * 64 + (c >> 1);
        }

    const f32x4 vzero = {0.f, 0.f, 0.f, 0.f};
    f32x4 o[4]; float l[4];
#pragma unroll
    for (int rr = 0; rr < 4; ++rr) { o[rr] = vzero; l[rr] = 0.f; }

    int nIter = (b0 + 7) >> 2;             // T = b0+4 staged subtiles
    __hip_bfloat16* Pw = &P[w][0];

    bf16x8 paP[2];          // prev-chunk P fragments (deferred PV)
    bf16x8 vfP[2][4];       // prev-chunk V fragments

    stage(0, 0);
    for (int ci = 0; ci < nIter; ++ci) {
        int cb = ci & 1;
        if (ci > 0) asm volatile("s_barrier" ::: "memory");      // buf cb^1 free
        if (ci + 1 < nIter) {
            stage(ci + 1, cb ^ 1);
            asm volatile("s_waitcnt vmcnt(4)" ::: "memory");     // chunk ci landed
        } else {
            asm volatile("s_waitcnt vmcnt(0)" ::: "memory");
        }
        asm volatile("s_barrier" ::: "memory");                  // chunk ci visible

        bf16x8 ka[4], kb8[4];
#pragma unroll
        for (int s = 0; s < 4; ++s) {
            ka[s]  = *(const bf16x8*)&KL[cb][kfo[s][0]];
            kb8[s] = *(const bf16x8*)&KL[cb][kfo[s][1]];
        }
        // scores: D[m=q][n=key]; lane: col=key=l15, row q=quad*4+rr
        f32x4 sc[4];
        __builtin_amdgcn_s_setprio(1);
#pragma unroll
        for (int s = 0; s < 4; ++s)
            sc[s] = mfma_bf16(qb, kb8[s], mfma_bf16(qa, ka[s], vzero));
        __builtin_amdgcn_s_setprio(0);
        bf16x8 vf[2][4];
#pragma unroll
        for (int p2 = 0; p2 < 2; ++p2)
#pragma unroll
            for (int tt = 0; tt < 4; ++tt)
                vf[p2][tt] = *(const bf16x8*)&VL[cb][vfo[p2][tt]];

        // exp + mask, accumulate l, write P[q][64 keys] (stride 68)
#pragma unroll
        for (int s = 0; s < 4; ++s) {
            bool a = active(4 * ci + s);
#pragma unroll
            for (int rr = 0; rr < 4; ++rr) {
                float pv = a ? __expf(sc[s][rr]) : 0.f;
                l[rr] += pv;
                Pw[(quad * 4 + rr) * 68 + s * 16 + l15] = __float2bfloat16(pv);
            }
        }
        // deferred PV of chunk ci-1: pure-register MFMAs execute while the
        // P(ci) writes drain -- hides the LDS round-trip latency.
        if (ci > 0) {
            __builtin_amdgcn_s_setprio(1);
#pragma unroll
            for (int p2 = 0; p2 < 2; ++p2)
#pragma unroll
                for (int tt = 0; tt < 4; ++tt)
                    o[tt] = mfma_bf16(paP[p2], vfP[p2][tt], o[tt]);
            __builtin_amdgcn_s_setprio(0);
        }
        asm volatile("s_waitcnt lgkmcnt(0)" ::: "memory");       // P(ci) visible
        bf16x8 pa[2];
#pragma unroll
        for (int p2 = 0; p2 < 2; ++p2) {
            union { bf16x4 h[2]; bf16x8 v; } u;
            u.h[0] = *(const bf16x4*)(Pw + l15 * 68 + p2 * 32 + quad * 8);
            u.h[1] = *(const bf16x4*)(Pw + l15 * 68 + p2 * 32 + quad * 8 + 4);
            pa[p2] = u.v;
        }
        // no drain: pa consumed next iteration (compiler emits counted wait)
#pragma unroll
        for (int p2 = 0; p2 < 2; ++p2) {
            paP[p2] = pa[p2];
#pragma unroll
            for (int tt = 0; tt < 4; ++tt) vfP[p2][tt] = vf[p2][tt];
        }
    }
    // final PV for the last chunk
    asm volatile("s_waitcnt lgkmcnt(0)" ::: "memory");
    __builtin_amdgcn_s_setprio(1);
#pragma unroll
    for (int p2 = 0; p2 < 2; ++p2)
#pragma unroll
        for (int tt = 0; tt < 4; ++tt)
            o[tt] = mfma_bf16(paP[p2], vfP[p2][tt], o[tt]);
    __builtin_amdgcn_s_setprio(0);

    // epilogue: per-wave, direct write (no merge needed)
    int b = bh / 12, h = bh - b * 12;
    int seqbase = qblk * 16;
#pragma unroll
    for (int rr = 0; rr < 4; ++rr) {
        float lr = l[rr];
#pragma unroll
        for (int msk = 1; msk < 16; msk <<= 1) lr += __shfl_xor(lr, msk, 16);
        float inv = 1.f / lr;
        long row = b * 2048 + seqbase + quad * 4 + rr;
#pragma unroll
        for (int tt = 0; tt < 4; ++tt)
            out[row * 768 + h * 64 + tt * 16 + l15] = __float2bfloat16(o[tt][rr] * inv);
    }
}

// ---------------- 128xTN bf16 GEMM, 3 LDS buffers, depth-2 pipeline.
// R21: L3-traffic model + XCD-aware bijective swizzle (288.5->280.6).
// R22: mlp2 TN=128 split-K=4 (->278.9). R24: depth-1 gave tile i+1 only
// ONE iteration (~250-400cy) to land before its vmcnt -- less than L2
// (~200cy marginal) and far less than HBM (~900cy) latency, exposing
// load latency at every iteration (MfmaUtil stuck 12-22%). Depth-2:
// prologue stages tiles 0,1; per iter stage(i+2) into buf (i+2)%3
// (safe: top barrier proves compute i-1, which read that buf, is done),
// then vmcnt(2*NINST) -- two tiles in flight, landing window doubled.
// LDS 48KB @TN=128 (3 blocks/CU, = grid) / 36KB @TN=64 (4/CU).
// XOR-swizzled conflict-free ds_read_b128 unchanged.
// MODE 1: Cf = mods[gate]*acc + resid   (attn proj + gate + residual)
// MODE 2: Cb = bf16(fast_gelu(acc + bias))   (mlp1)
// MODE 4: qkv + fused RoPE epilogue -> q (x0.125), k, vT bf16 (TN=64 only).
// MODE 5: split-K partial: Cb[z*M*N + row*N+col] = bf16(acc).
template <int MODE, int TN>
__global__ __launch_bounds__(TN == 128 ? 256 : 128) void k_gemm(
    const __hip_bfloat16* __restrict__ A, const __hip_bfloat16* __restrict__ W,
    float* __restrict__ Cf, __hip_bfloat16* __restrict__ Cb,
    const float* __restrict__ bias, const float* __restrict__ mods, int gateOff,
    const float* __restrict__ resid, const float* __restrict__ cosb,
    const float* __restrict__ sinb, __hip_bfloat16* __restrict__ qo,
    __hip_bfloat16* __restrict__ ko, __hip_bfloat16* __restrict__ vo,
    int M, int N, int K, int lda) {
    constexpr int NW = (TN == 128) ? 4 : 2;
    constexpr int ACH = 512 / (NW * 64);
    constexpr int BCH = (TN * 4) / (NW * 64);
    constexpr int NINST = ACH + BCH;
    constexpr int BOFF = 3 * 128 * 32;                   // B buffers base
    constexpr int SM_SHORTS = 3 * 128 * 32 + 3 * TN * 32;
    __shared__ __align__(16) __hip_bfloat16 SM[SM_SHORTS];
    int t = threadIdx.x;
    int wave = t >> 6, lane = t & 63, l15 = lane & 15, quad = lane >> 4;
    int wr = (TN == 128) ? (wave >> 1) : wave;
    int wc = (TN == 128) ? (wave & 1) : 0;
    int sw8 = (quad ^ ((l15 >> 1) & 3)) * 8;
    // XCD-aware swizzle: each XCD owns bm in [4*xcd, 4*xcd+4) for all bn.
    int lin = (int)blockIdx.x + 32 * (int)blockIdx.y;
    int slot = lin >> 3;
    long bm = 4 * (lin & 7) + (slot & 3);
    long bn = slot >> 2;
    const __hip_bfloat16* Ab = A + bm * 128 * lda + (long)blockIdx.z * K;
    const __hip_bfloat16* Wb = W + bn * TN * lda + (long)blockIdx.z * K;

    long soffA[ACH], soffB[BCH];
#pragma unroll
    for (int cc = 0; cc < ACH; ++cc) {
        int chunk = cc * NW * 64 + t;
        int row = chunk >> 2;
        int c = (chunk & 3) ^ ((row >> 1) & 3);
        soffA[cc] = (long)row * lda + c * 8;
    }
#pragma unroll
    for (int cc = 0; cc < BCH; ++cc) {
        int chunk = cc * NW * 64 + t;
        int row = chunk >> 2;
        int c = (chunk & 3) ^ ((row >> 1) & 3);
        soffB[cc] = (long)row * lda + c * 8;
    }
    auto stage = [&](int k0, int buf) {
        char* lAc = (char*)(SM + buf * 4096);
        char* lBc = (char*)(SM + BOFF + buf * (TN * 32));
#pragma unroll
        for (int cc = 0; cc < ACH; ++cc)
            async_ld16(Ab + soffA[cc] + k0, lAc + cc * (NW * 1024) + wave * 1024);
#pragma unroll
        for (int cc = 0; cc < BCH; ++cc)
            async_ld16(Wb + soffB[cc] + k0, lBc + cc * (NW * 1024) + wave * 1024);
    };

    f32x4 acc[4][4];
#pragma unroll
    for (int i = 0; i < 4; ++i)
#pragma unroll
        for (int j = 0; j < 4; ++j) acc[i][j] = (f32x4){0.f, 0.f, 0.f, 0.f};

    int nIter = K / 32;
    stage(0, 0);
    if (nIter > 1) stage(32, 1);
    for (int i = 0; i < nIter; ++i) {
        int cb = i % 3;
        if (i > 0) asm volatile("s_barrier" ::: "memory");   // buf (i-1)%3 free
        if (i + 2 < nIter) {
            stage((i + 2) * 32, (i + 2) % 3);
            asm volatile("s_waitcnt vmcnt(%0)" :: "n"(2 * NINST) : "memory");  // tile i landed
        } else if (i + 1 < nIter) {
            asm volatile("s_waitcnt vmcnt(%0)" :: "n"(NINST) : "memory");
        } else {
            asm volatile("s_waitcnt vmcnt(0)" ::: "memory");
        }
        asm volatile("s_barrier" ::: "memory");              // tile i visible
        bf16x8 af[4], bfr[4];
#pragma unroll
        for (int ii = 0; ii < 4; ++ii)
            af[ii] = *(const bf16x8*)&SM[cb * 4096 + (wr * 64 + ii * 16 + l15) * 32 + sw8];
#pragma unroll
        for (int j = 0; j < 4; ++j)
            bfr[j] = *(const bf16x8*)&SM[BOFF + cb * (TN * 32) + (wc * 64 + j * 16 + l15) * 32 + sw8];
#pragma unroll
        for (int ii = 0; ii < 4; ++ii)
#pragma unroll
            for (int j = 0; j < 4; ++j)
                acc[ii][j] = mfma_bf16(af[ii], bfr[j], acc[ii][j]);
    }

    if (MODE == 4) {
        static_assert(MODE != 4 || TN == 64, "MODE4 requires TN=64");
        int th = (int)bn / 12, h = (int)bn % 12;   // head-col = bn (TN=64)
        int sbase = ((int)bm * 128) & 2047;
        int b = ((int)bm * 128) >> 11;
        long bh_ = (long)b * 12 + h;
        if (th == 2) {
            // vT: RoPE into LDS [64 d][132 s] transpose tile (reuses staging
            // SMEM), then coalesced 256B dword rows. Replaces 2B/4KB-stride
            // scattered stores (64 txns/inst) with 1-txn coalesced stores.
            __syncthreads();
#pragma unroll
            for (int i = 0; i < 4; ++i) {
                int sl = wr * 64 + i * 16 + quad * 4;
#pragma unroll
                for (int j = 0; j < 2; ++j) {
                    int dh = j * 16 + l15;
                    bf16x4 p0, p1;
#pragma unroll
                    for (int r = 0; r < 4; ++r) {
                        int s = sbase + sl + r;
                        const float* cbp = cosb + s * 64;
                        const float* sbp = sinb + s * 64;
                        float a0f = acc[i][j][r], a1f = acc[i][j + 2][r];
                        p0[r] = f2bf_s(a0f * cbp[dh] - a1f * sbp[dh]);
                        p1[r] = f2bf_s(a1f * cbp[dh + 32] + a0f * sbp[dh + 32]);
                    }
                    *(bf16x4*)(SM + dh * 132 + sl) = p0;
                    *(bf16x4*)(SM + (dh + 32) * 132 + sl) = p1;
                }
            }
            __syncthreads();
            __hip_bfloat16* dst = vo + bh_ * 64 * 2048;
#pragma unroll
            for (int dd = 0; dd < 32; ++dd) {
                int d = wr * 32 + dd;
                unsigned pv = *(const unsigned*)(SM + d * 132 + lane * 2);
                *(unsigned*)(dst + (long)d * 2048 + sbase + lane * 2) = pv;
            }
            return;
        }
        // th 0/1: q (x0.125) / k, direct stores (16-lane 32B runs)
        float qs = (th == 0) ? 0.125f : 1.f;
        __hip_bfloat16* base = (th == 0) ? qo : ko;
#pragma unroll
        for (int i = 0; i < 4; ++i) {
#pragma unroll
            for (int r = 0; r < 4; ++r) {
                int s = sbase + wr * 64 + i * 16 + quad * 4 + r;
                const float* cbp = cosb + s * 64;
                const float* sbp = sinb + s * 64;
                __hip_bfloat16* d = base + (bh_ * 2048 + s) * 64;
#pragma unroll
                for (int j = 0; j < 2; ++j) {
                    int dh = j * 16 + l15;
                    float a0f = acc[i][j][r], a1f = acc[i][j + 2][r];
                    float o0 = a0f * cbp[dh] - a1f * sbp[dh];
                    float o1 = a1f * cbp[dh + 32] + a0f * sbp[dh + 32];
                    d[dh]      = __float2bfloat16(o0 * qs);
                    d[dh + 32] = __float2bfloat16(o1 * qs);
                }
            }
        }
        return;
    }

#pragma unroll
    for (int i = 0; i < 4; ++i) {
#pragma unroll
        for (int j = 0; j < 4; ++j) {
#pragma unroll
            for (int r = 0; r < 4; ++r) {
                int row = (int)bm * 128 + wr * 64 + i * 16 + quad * 4 + r;
                int col = (int)bn * TN + wc * 64 + j * 16 + l15;
                float v = acc[i][j][r];
                long idx = (long)row * N + col;
                if (MODE == 1) {
                    Cf[idx] = mods[(row >> 11) * 4608 + gateOff + col] * v + resid[idx];
                } else if (MODE == 2) {
                    Cb[idx] = __float2bfloat16(fast_gelu(v + bias[col]));
                } else {   // MODE 5: split-K partial
                    Cb[(long)blockIdx.z * M * N + idx] = __float2bfloat16(v);
                }
            }
        }
    }
}

extern "C" void kernel_launch(void* const* d_in, const int* in_sizes, int n_in,
                              void* d_out, int out_size, void* d_ws, size_t ws_size,
                              hipStream_t stream) {
    const float* x    = (const float*)d_in[0];
    const float* c    = (const float*)d_in[1];
    const float* cosb = (const float*)d_in[2];
    const float* sinb = (const float*)d_in[3];
    // d_in[4] = mask: unused, computed analytically
    const float* n1w  = (const float*)d_in[5];
    const float* qkvw = (const float*)d_in[6];
    const float* aow  = (const float*)d_in[7];
    const float* n2w  = (const float*)d_in[8];
    const float* w1   = (const float*)d_in[9];
    const float* b1   = (const float*)d_in[10];
    const float* w2   = (const float*)d_in[11];
    const float* b2   = (const float*)d_in[12];
    const float* alw  = (const float*)d_in[13];
    const float* alb  = (const float*)d_in[14];

    char* ws = (char*)d_ws;
    size_t off = 0;
    auto alloc = [&](size_t bytes) -> void* {
        void* p = ws + off;
        off += (bytes + 255) & ~(size_t)255;
        return p;
    };
    float*          mods = (float*)alloc(2 * 4608 * 4);
    __hip_bfloat16* hbuf = (__hip_bfloat16*)alloc((size_t)4096 * 768 * 2);
    __hip_bfloat16* qb   = (__hip_bfloat16*)alloc((size_t)24 * 2048 * 64 * 2);
    __hip_bfloat16* kb   = (__hip_bfloat16*)alloc((size_t)24 * 2048 * 64 * 2);
    __hip_bfloat16* vT   = (__hip_bfloat16*)alloc((size_t)24 * 64 * 2048 * 2);
    __hip_bfloat16* abuf = (__hip_bfloat16*)alloc((size_t)4096 * 768 * 2);
    float*          x2   = (float*)alloc((size_t)4096 * 768 * 4);
    __hip_bfloat16* h2   = (__hip_bfloat16*)alloc((size_t)4096 * 768 * 2);
    __hip_bfloat16* m1   = (__hip_bfloat16*)alloc((size_t)4096 * 3072 * 2);
    __hip_bfloat16* m2p  = (__hip_bfloat16*)alloc((size_t)4 * 4096 * 768 * 2);
    __hip_bfloat16* wq   = (__hip_bfloat16*)alloc((size_t)2304 * 768 * 2);
    __hip_bfloat16* wa   = (__hip_bfloat16*)alloc((size_t)768 * 768 * 2);
    __hip_bfloat16* w1b  = (__hip_bfloat16*)alloc((size_t)3072 * 768 * 2);
    __hip_bfloat16* w2b  = (__hip_bfloat16*)alloc((size_t)768 * 3072 * 2);

    // R23: vectorized convert (8/thread) -> 3456+36 blocks (was 27684)
    k_pre<<<3492, 256, 0, stream>>>(qkvw, wq, 2304 * 768, aow, wa, 768 * 768,
                                    w1, w1b, 3072 * 768, w2, w2b, 768 * 3072,
                                    c, alw, alb, mods);
    k_ln_mod<<<1024, 256, 0, stream>>>(x, n1w, mods, 0, 768, hbuf);
    // qkv GEMM + fused RoPE -> q, k, vT (64-tile: 1152 blocks, XCD-swizzled)
    k_gemm<4, 64><<<dim3(32, 36), 128, 0, stream>>>(hbuf, wq, nullptr, nullptr, nullptr, nullptr, 0,
                                                    nullptr, cosb, sinb, qb, kb, vT,
                                                    4096, 2304, 768, 768);
    k_attn<<<768, 256, 0, stream>>>(qb, kb, vT, abuf);
    k_gemm<1, 64><<<dim3(32, 12), 128, 0, stream>>>(abuf, wa, x2, nullptr, nullptr, mods, 1536,
                                                    x, nullptr, nullptr, nullptr, nullptr, nullptr,
                                                    4096, 768, 768, 768);
    k_ln_mod<<<1024, 256, 0, stream>>>(x2, n2w, mods, 2304, 3072, h2);
    // mlp1: 128x128 (768 blocks = 3/CU, lowest-traffic tiling, XCD-swizzled)
    k_gemm<2, 128><<<dim3(32, 24), 256, 0, stream>>>(h2, w1b, nullptr, m1, b1, nullptr, 0,
                                                     nullptr, nullptr, nullptr, nullptr, nullptr, nullptr,
                                                     4096, 3072, 768, 768);
    // mlp2: TN=128 + split-K=4 (768 blocks = 3/CU)
    k_gemm<5, 128><<<dim3(32, 6, 4), 256, 0, stream>>>(m1, w2b, nullptr, m2p, nullptr, nullptr, 0,
                                                       nullptr, nullptr, nullptr, nullptr, nullptr, nullptr,
                                                       4096, 768, 768, 3072);
    k_red<<<1536, 256, 0, stream>>>(m2p, x2, mods, b2, (float*)d_out);
}

// Round 13
// 275.011 us; speedup vs baseline: 1.0014x; 1.0014x over previous
//
#include <hip/hip_runtime.h>
#include <hip/hip_bf16.h>

#define EPS 1e-5f

typedef __attribute__((ext_vector_type(8))) short bf16x8;
typedef __attribute__((ext_vector_type(4))) short bf16x4;
typedef __attribute__((ext_vector_type(4))) float f32x4;

__device__ __forceinline__ f32x4 mfma_bf16(bf16x8 a, bf16x8 b, f32x4 c) {
    return __builtin_amdgcn_mfma_f32_16x16x32_bf16(a, b, c, 0, 0, 0);
}

__device__ __forceinline__ void async_ld16(const void* g, void* l) {
    __builtin_amdgcn_global_load_lds(
        (const __attribute__((address_space(1))) void*)g,
        (__attribute__((address_space(3))) void*)l, 16, 0, 0);
}

// fast gelu: 0.5v(1+tanh z) == v * sigmoid(2z); one v_exp + one rcp.
__device__ __forceinline__ float fast_gelu(float v) {
    float z2 = 1.5957691216057308f * (v + 0.044715f * v * v * v);
    float e = __expf(z2);
    return v * e / (e + 1.f);
}

__device__ __forceinline__ float bf2f(short s) {
    union { float f; unsigned u; } v;
    v.u = ((unsigned)(unsigned short)s) << 16;
    return v.f;
}

__device__ __forceinline__ short f2bf_s(float x) {
    union { __hip_bfloat16 h; short s; } cv;
    cv.h = __float2bfloat16(x);
    return cv.s;
}

// 8-wide f32 -> bf16 convert (32B read, 16B write)
__device__ __forceinline__ void cvt8(const float* __restrict__ src,
                                     __hip_bfloat16* __restrict__ dst) {
    float4 v0 = *(const float4*)src;
    float4 v1 = *(const float4*)(src + 4);
    bf16x8 r;
    r[0] = f2bf_s(v0.x); r[1] = f2bf_s(v0.y); r[2] = f2bf_s(v0.z); r[3] = f2bf_s(v0.w);
    r[4] = f2bf_s(v1.x); r[5] = f2bf_s(v1.y); r[6] = f2bf_s(v1.z); r[7] = f2bf_s(v1.w);
    *(bf16x8*)dst = r;
}

// ---------------- merged pre-work: f32->bf16 weight convert (blocks 0..3455,
// 8 elems/thread, vectorized: R23 dispatch-overhead fix, was 27648 scalar
// blocks) + adaLN mods[b][i] = c[b].adaLN_w[i] + adaLN_b[i] (last 36 blocks)
__global__ void k_pre(const float* __restrict__ a, __hip_bfloat16* __restrict__ oa, int na,
                      const float* __restrict__ b, __hip_bfloat16* __restrict__ ob, int nb,
                      const float* __restrict__ c, __hip_bfloat16* __restrict__ oc, int nc,
                      const float* __restrict__ d, __hip_bfloat16* __restrict__ od, int nd,
                      const float* __restrict__ cond, const float* __restrict__ alw,
                      const float* __restrict__ alb, float* __restrict__ mods) {
    if (blockIdx.x >= 3456) {
        int i = (blockIdx.x - 3456) * 256 + threadIdx.x;   // 0..9215
        int bb = i / 4608, row = i - bb * 4608;
        const float4* cv = (const float4*)(cond + bb * 128);
        const float4* wv = (const float4*)(alw + (long)row * 128);
        float acc = 0.f;
#pragma unroll
        for (int k = 0; k < 32; ++k) {
            float4 x = cv[k], y = wv[k];
            acc += x.x * y.x + x.y * y.y + x.z * y.z + x.w * y.w;
        }
        mods[i] = acc + alb[row];
        return;
    }
    long i = ((long)blockIdx.x * 256 + threadIdx.x) * 8;   // all sizes %8==0
    if (i < na) { cvt8(a + i, oa + i); return; }
    i -= na;
    if (i < nb) { cvt8(b + i, ob + i); return; }
    i -= nb;
    if (i < nc) { cvt8(c + i, oc + i); return; }
    i -= nc;
    if (i < nd) cvt8(d + i, od + i);
}

// ---------------- fused LayerNorm + adaLN modulate, 1 wave per token,
// 4 tokens per 256-thread block (R23: was 4096 blocks x 64 threads).
__global__ __launch_bounds__(256) void k_ln_mod(
        const float* __restrict__ x, const float* __restrict__ w,
        const float* __restrict__ mods, int shiftOff, int scaleOff,
        __hip_bfloat16* __restrict__ out) {
    int token = blockIdx.x * 4 + (threadIdx.x >> 6);    // 0..4095
    int lane = threadIdx.x & 63;
    const float4* xr = (const float4*)(x + (long)token * 768);
    float4 v0 = xr[lane], v1 = xr[lane + 64], v2 = xr[lane + 128];
    float s  = v0.x + v0.y + v0.z + v0.w + v1.x + v1.y + v1.z + v1.w + v2.x + v2.y + v2.z + v2.w;
    float ss = v0.x*v0.x + v0.y*v0.y + v0.z*v0.z + v0.w*v0.w
             + v1.x*v1.x + v1.y*v1.y + v1.z*v1.z + v1.w*v1.w
             + v2.x*v2.x + v2.y*v2.y + v2.z*v2.z + v2.w*v2.w;
#pragma unroll
    for (int m = 32; m >= 1; m >>= 1) { s += __shfl_xor(s, m); ss += __shfl_xor(ss, m); }
    float mu = s * (1.f / 768.f);
    float var = ss * (1.f / 768.f) - mu * mu;
    float rs = rsqrtf(var + EPS);
    int b = token >> 11;
    const float* sh = mods + b * 4608 + shiftOff;
    const float* sc = mods + b * 4608 + scaleOff;
    __hip_bfloat16* o = out + (long)token * 768;
    float4 vv[3] = {v0, v1, v2};
#pragma unroll
    for (int kk = 0; kk < 3; ++kk) {
        int cbase = (lane + 64 * kk) * 4;
        const float* p = (const float*)&vv[kk];
#pragma unroll
        for (int j = 0; j < 4; ++j) {
            int col = cbase + j;
            float hv = (p[j] - mu) * rs * w[col] * (1.f + sc[col]) + sh[col];
            o[col] = __float2bfloat16(hv);
        }
    }
}

// ---------------- split-K reduce + mlp2 epilogue (4 partials), grid-stride
// (R23: 1536 blocks): out = x2 + gate*(p0+p1+p2+p3 + bias).
__global__ __launch_bounds__(256) void k_red(
        const __hip_bfloat16* __restrict__ p, const float* __restrict__ x2,
        const float* __restrict__ mods, const float* __restrict__ bias,
        float* __restrict__ out) {
    for (long tt = (long)blockIdx.x * 256 + threadIdx.x; tt < 786432;
         tt += (long)gridDim.x * 256) {
        long base = tt * 4;
        int col = (int)(base % 768);
        int row = (int)(base / 768);
        int b = row >> 11;
        float sx = 0.f, sy = 0.f, sz = 0.f, sw = 0.f;
#pragma unroll
        for (int z = 0; z < 4; ++z) {
            short4 a = *(const short4*)(p + (long)z * 3145728 + base);
            sx += bf2f(a.x); sy += bf2f(a.y); sz += bf2f(a.z); sw += bf2f(a.w);
        }
        float4 xr = *(const float4*)(x2 + base);
        float4 gt = *(const float4*)(mods + b * 4608 + 3840 + col);
        float4 bs = *(const float4*)(bias + col);
        float4 o;
        o.x = xr.x + gt.x * (sx + bs.x);
        o.y = xr.y + gt.y * (sy + bs.y);
        o.z = xr.z + gt.z * (sz + bs.z);
        o.w = xr.w + gt.w * (sw + bs.w);
        *(float4*)(out + base) = o;
    }
}

// ---------------- block-sparse flash attention, no-max softmax.
// R18: coalesced LDS staging of K/V (shared across 4 waves/workgroup) cut
// scattered-gather txns ~10x -> 56 -> ~36us. R19 deferred-PV pipeline:
// neutral (kept). Structure: workgroup = 4 q-blocks sharing a prefix,
// w=0..3 <-> (fl,blk) in {(0,b0),(1,b0),(0,b0+1),(1,b0+1)}; K/V chunks
// staged via coalesced global_load_lds (dbuf, vmcnt(4)), XOR-swizzled via
// pre-swizzled GLOBAL source (LDS dest linear, m104/m173); conflict-free
// ds_read_b128 fragments. Per-wave act masks; tail subtiles masked p=0.
__global__ __launch_bounds__(256) void k_attn(
    const __hip_bfloat16* __restrict__ q, const __hip_bfloat16* __restrict__ k,
    const __hip_bfloat16* __restrict__ vT, __hip_bfloat16* __restrict__ out) {
    __shared__ __hip_bfloat16 KL[2][64 * 64];   // [buf][key(64)][dim(64)] swizzled
    __shared__ __hip_bfloat16 VL[2][64 * 64];   // [buf][dim(64)][lkey(64)] swizzled
    __shared__ __hip_bfloat16 P[4][16 * 68];    // per-wave P tile
    int tid = threadIdx.x;
    int w = tid >> 6, lane = tid & 63, l15 = lane & 15, quad = lane >> 4;
    int idx = blockIdx.x;                  // 0..767
    int bh = idx % 24;                     // fastest: spreads across XCDs
    int gi = idx / 24;                     // 0..31
    int b0 = 62 - 2 * gi;                  // longest prefix first
    int fl = w & 1, blk = b0 + (w >> 1);
    int qblk = fl * 64 + blk;

    const __hip_bfloat16* Q = q + ((long)bh * 2048 + qblk * 16) * 64;
    bf16x8 qa = *(const bf16x8*)(Q + l15 * 64 + quad * 8);
    bf16x8 qb = *(const bf16x8*)(Q + l15 * 64 + 32 + quad * 8);
    const __hip_bfloat16* K = k + (long)bh * 2048 * 64;
    const __hip_bfloat16* V = vT + (long)bh * 64 * 2048;

    // staged subtile t -> global key base (clamped to 0 when out of range)
    auto kbase = [&](int t) -> int {
        if (t < b0 + 2) return 1024 + t * 16;
        if (t == b0 + 2) return b0 * 16;
        if (t == b0 + 3) return (b0 + 1) * 16;
        return 0;
    };
    // per-wave subtile activity (wave-uniform)
    auto active = [&](int t) -> bool {
        if (w == 0) return t < b0 || t == b0 + 2;
        if (w == 1) return t < b0 + 1;
        if (w == 2) return t < b0 + 1 || t == b0 + 3;
        return t < b0 + 2;
    };

    // staging decode constants (per thread: 2 K instrs + 2 V instrs)
    int kkr[2], kbs[2], vsi[2], vki[2];
#pragma unroll
    for (int i = 0; i < 2; ++i) {
        int o = i * 4096 + tid * 16;
        kkr[i] = o >> 7;
        int b = o & 127;
        kbs[i] = b ^ ((kkr[i] & 7) << 4);
        int lk2 = b ^ ((kkr[i] & 7) << 4);   // same row index for V decode
        vsi[i] = lk2 >> 5;
        vki[i] = (lk2 & 31) >> 1;
    }
    auto stage = [&](int ci, int buf) {
#pragma unroll
        for (int i = 0; i < 2; ++i) {
            int gk = kbase(4 * ci + (kkr[i] >> 4)) + (kkr[i] & 15);
            async_ld16(K + (long)gk * 64 + (kbs[i] >> 1),
                       (char*)&KL[buf][0] + i * 4096 + tid * 16);
        }
#pragma unroll
        for (int i = 0; i < 2; ++i) {
            int gk = kbase(4 * ci + vsi[i]) + vki[i];
            async_ld16(V + (long)kkr[i] * 2048 + gk,
                       (char*)&VL[buf][0] + i * 4096 + tid * 16);
        }
    };

    // fragment LDS offsets (shorts), swizzle matches staging
    int kfo[4][2], vfo[2][4];
#pragma unroll
    for (int s = 0; s < 4; ++s)
#pragma unroll
        for (int h = 0; h < 2; ++h)
            kfo[s][h] = (s * 16 + l15) * 64 +
                        (((h * 64 + quad * 16) ^ ((l15 & 7) << 4)) >> 1);
#pragma unroll
    for (int p2 = 0; p2 < 2; ++p2)
#pragma unroll
        for (int tt = 0; tt < 4; ++tt) {
            int d = tt * 16 + l15;
            int c = (p2 * 64 + (quad >> 1) * 32 + (quad & 1) * 16) ^ ((l15 & 7) << 4);
            vfo[p2][tt] = d * 64 + (c >> 1);
        }

    const f32x4 vzero = {0.f, 0.f, 0.f, 0.f};
    f32x4 o[4]; float l[4];
#pragma unroll
    for (int rr = 0; rr < 4; ++rr) { o[rr] = vzero; l[rr] = 0.f; }

    int nIter = (b0 + 7) >> 2;             // T = b0+4 staged subtiles
    __hip_bfloat16* Pw = &P[w][0];

    bf16x8 paP[2];          // prev-chunk P fragments (deferred PV)
    bf16x8 vfP[2][4];       // prev-chunk V fragments

    stage(0, 0);
    for (int ci = 0; ci < nIter; ++ci) {
        int cb = ci & 1;
        if (ci > 0) asm volatile("s_barrier" ::: "memory");      // buf cb^1 free
        if (ci + 1 < nIter) {
            stage(ci + 1, cb ^ 1);
            asm volatile("s_waitcnt vmcnt(4)" ::: "memory");     // chunk ci landed
        } else {
            asm volatile("s_waitcnt vmcnt(0)" ::: "memory");
        }
        asm volatile("s_barrier" ::: "memory");                  // chunk ci visible

        bf16x8 ka[4], kb8[4];
#pragma unroll
        for (int s = 0; s < 4; ++s) {
            ka[s]  = *(const bf16x8*)&KL[cb][kfo[s][0]];
            kb8[s] = *(const bf16x8*)&KL[cb][kfo[s][1]];
        }
        // scores: D[m=q][n=key]; lane: col=key=l15, row q=quad*4+rr
        f32x4 sc[4];
        __builtin_amdgcn_s_setprio(1);
#pragma unroll
        for (int s = 0; s < 4; ++s)
            sc[s] = mfma_bf16(qb, kb8[s], mfma_bf16(qa, ka[s], vzero));
        __builtin_amdgcn_s_setprio(0);
        bf16x8 vf[2][4];
#pragma unroll
        for (int p2 = 0; p2 < 2; ++p2)
#pragma unroll
            for (int tt = 0; tt < 4; ++tt)
                vf[p2][tt] = *(const bf16x8*)&VL[cb][vfo[p2][tt]];

        // exp + mask, accumulate l, write P[q][64 keys] (stride 68)
#pragma unroll
        for (int s = 0; s < 4; ++s) {
            bool a = active(4 * ci + s);
#pragma unroll
            for (int rr = 0; rr < 4; ++rr) {
                float pv = a ? __expf(sc[s][rr]) : 0.f;
                l[rr] += pv;
                Pw[(quad * 4 + rr) * 68 + s * 16 + l15] = __float2bfloat16(pv);
            }
        }
        // deferred PV of chunk ci-1: pure-register MFMAs execute while the
        // P(ci) writes drain -- hides the LDS round-trip latency.
        if (ci > 0) {
            __builtin_amdgcn_s_setprio(1);
#pragma unroll
            for (int p2 = 0; p2 < 2; ++p2)
#pragma unroll
                for (int tt = 0; tt < 4; ++tt)
                    o[tt] = mfma_bf16(paP[p2], vfP[p2][tt], o[tt]);
            __builtin_amdgcn_s_setprio(0);
        }
        asm volatile("s_waitcnt lgkmcnt(0)" ::: "memory");       // P(ci) visible
        bf16x8 pa[2];
#pragma unroll
        for (int p2 = 0; p2 < 2; ++p2) {
            union { bf16x4 h[2]; bf16x8 v; } u;
            u.h[0] = *(const bf16x4*)(Pw + l15 * 68 + p2 * 32 + quad * 8);
            u.h[1] = *(const bf16x4*)(Pw + l15 * 68 + p2 * 32 + quad * 8 + 4);
            pa[p2] = u.v;
        }
        // no drain: pa consumed next iteration (compiler emits counted wait)
#pragma unroll
        for (int p2 = 0; p2 < 2; ++p2) {
            paP[p2] = pa[p2];
#pragma unroll
            for (int tt = 0; tt < 4; ++tt) vfP[p2][tt] = vf[p2][tt];
        }
    }
    // final PV for the last chunk
    asm volatile("s_waitcnt lgkmcnt(0)" ::: "memory");
    __builtin_amdgcn_s_setprio(1);
#pragma unroll
    for (int p2 = 0; p2 < 2; ++p2)
#pragma unroll
        for (int tt = 0; tt < 4; ++tt)
            o[tt] = mfma_bf16(paP[p2], vfP[p2][tt], o[tt]);
    __builtin_amdgcn_s_setprio(0);

    // epilogue: per-wave, direct write (no merge needed)
    int b = bh / 12, h = bh - b * 12;
    int seqbase = qblk * 16;
#pragma unroll
    for (int rr = 0; rr < 4; ++rr) {
        float lr = l[rr];
#pragma unroll
        for (int msk = 1; msk < 16; msk <<= 1) lr += __shfl_xor(lr, msk, 16);
        float inv = 1.f / lr;
        long row = b * 2048 + seqbase + quad * 4 + rr;
#pragma unroll
        for (int tt = 0; tt < 4; ++tt)
            out[row * 768 + h * 64 + tt * 16 + l15] = __float2bfloat16(o[tt][rr] * inv);
    }
}

// ---------------- 128xTN bf16 GEMM, regime-dependent pipeline depth.
// R21: L3-traffic model + XCD-aware bijective swizzle (288.5->280.6).
// R22: mlp2 TN=128 split-K=4 (->278.9). R24 depth-2 everywhere: NET ZERO
// but SPLIT -- mlp1 (TN=128, L3-BW-bound) regressed 7us (deeper prefetch
// just queues a saturated path; T14-null-on-BW-bound), TN=64 kernels
// (latency-exposed) gained the same back. R25: DEPTH = 1 for TN=128
// (2 buffers, the R9 config), DEPTH = 2 for TN=64 (3 buffers, keeps the
// measured qkv/proj gain). XOR-swizzled conflict-free ds_read_b128.
// MODE 1: Cf = mods[gate]*acc + resid   (attn proj + gate + residual)
// MODE 2: Cb = bf16(fast_gelu(acc + bias))   (mlp1)
// MODE 4: qkv + fused RoPE epilogue -> q (x0.125), k, vT bf16 (TN=64 only).
// MODE 5: split-K partial: Cb[z*M*N + row*N+col] = bf16(acc).
template <int MODE, int TN>
__global__ __launch_bounds__(TN == 128 ? 256 : 128) void k_gemm(
    const __hip_bfloat16* __restrict__ A, const __hip_bfloat16* __restrict__ W,
    float* __restrict__ Cf, __hip_bfloat16* __restrict__ Cb,
    const float* __restrict__ bias, const float* __restrict__ mods, int gateOff,
    const float* __restrict__ resid, const float* __restrict__ cosb,
    const float* __restrict__ sinb, __hip_bfloat16* __restrict__ qo,
    __hip_bfloat16* __restrict__ ko, __hip_bfloat16* __restrict__ vo,
    int M, int N, int K, int lda) {
    constexpr int NW = (TN == 128) ? 4 : 2;
    constexpr int ACH = 512 / (NW * 64);
    constexpr int BCH = (TN * 4) / (NW * 64);
    constexpr int NINST = ACH + BCH;
    constexpr int DEPTH = (TN == 128) ? 1 : 2;
    constexpr int NBUF = DEPTH + 1;
    constexpr int BOFF = NBUF * 128 * 32;                // B buffers base
    constexpr int SM_SHORTS = NBUF * 128 * 32 + NBUF * TN * 32;
    __shared__ __align__(16) __hip_bfloat16 SM[SM_SHORTS];
    int t = threadIdx.x;
    int wave = t >> 6, lane = t & 63, l15 = lane & 15, quad = lane >> 4;
    int wr = (TN == 128) ? (wave >> 1) : wave;
    int wc = (TN == 128) ? (wave & 1) : 0;
    int sw8 = (quad ^ ((l15 >> 1) & 3)) * 8;
    // XCD-aware swizzle: each XCD owns bm in [4*xcd, 4*xcd+4) for all bn.
    int lin = (int)blockIdx.x + 32 * (int)blockIdx.y;
    int slot = lin >> 3;
    long bm = 4 * (lin & 7) + (slot & 3);
    long bn = slot >> 2;
    const __hip_bfloat16* Ab = A + bm * 128 * lda + (long)blockIdx.z * K;
    const __hip_bfloat16* Wb = W + bn * TN * lda + (long)blockIdx.z * K;

    long soffA[ACH], soffB[BCH];
#pragma unroll
    for (int cc = 0; cc < ACH; ++cc) {
        int chunk = cc * NW * 64 + t;
        int row = chunk >> 2;
        int c = (chunk & 3) ^ ((row >> 1) & 3);
        soffA[cc] = (long)row * lda + c * 8;
    }
#pragma unroll
    for (int cc = 0; cc < BCH; ++cc) {
        int chunk = cc * NW * 64 + t;
        int row = chunk >> 2;
        int c = (chunk & 3) ^ ((row >> 1) & 3);
        soffB[cc] = (long)row * lda + c * 8;
    }
    auto stage = [&](int k0, int buf) {
        char* lAc = (char*)(SM + buf * 4096);
        char* lBc = (char*)(SM + BOFF + buf * (TN * 32));
#pragma unroll
        for (int cc = 0; cc < ACH; ++cc)
            async_ld16(Ab + soffA[cc] + k0, lAc + cc * (NW * 1024) + wave * 1024);
#pragma unroll
        for (int cc = 0; cc < BCH; ++cc)
            async_ld16(Wb + soffB[cc] + k0, lBc + cc * (NW * 1024) + wave * 1024);
    };

    f32x4 acc[4][4];
#pragma unroll
    for (int i = 0; i < 4; ++i)
#pragma unroll
        for (int j = 0; j < 4; ++j) acc[i][j] = (f32x4){0.f, 0.f, 0.f, 0.f};

    int nIter = K / 32;
    stage(0, 0);
    if constexpr (DEPTH == 2) { if (nIter > 1) stage(32, 1); }
    for (int i = 0; i < nIter; ++i) {
        int cb = (NBUF == 2) ? (i & 1) : (i % 3);
        if (i > 0) asm volatile("s_barrier" ::: "memory");   // oldest buf free
        if constexpr (DEPTH == 1) {
            if (i + 1 < nIter) {
                stage((i + 1) * 32, cb ^ 1);
                asm volatile("s_waitcnt vmcnt(%0)" :: "n"(NINST) : "memory");  // tile i landed
            } else {
                asm volatile("s_waitcnt vmcnt(0)" ::: "memory");
            }
        } else {
            if (i + 2 < nIter) {
                stage((i + 2) * 32, (i + 2) % 3);
                asm volatile("s_waitcnt vmcnt(%0)" :: "n"(2 * NINST) : "memory");  // tile i landed
            } else if (i + 1 < nIter) {
                asm volatile("s_waitcnt vmcnt(%0)" :: "n"(NINST) : "memory");
            } else {
                asm volatile("s_waitcnt vmcnt(0)" ::: "memory");
            }
        }
        asm volatile("s_barrier" ::: "memory");              // tile i visible
        bf16x8 af[4], bfr[4];
#pragma unroll
        for (int ii = 0; ii < 4; ++ii)
            af[ii] = *(const bf16x8*)&SM[cb * 4096 + (wr * 64 + ii * 16 + l15) * 32 + sw8];
#pragma unroll
        for (int j = 0; j < 4; ++j)
            bfr[j] = *(const bf16x8*)&SM[BOFF + cb * (TN * 32) + (wc * 64 + j * 16 + l15) * 32 + sw8];
#pragma unroll
        for (int ii = 0; ii < 4; ++ii)
#pragma unroll
            for (int j = 0; j < 4; ++j)
                acc[ii][j] = mfma_bf16(af[ii], bfr[j], acc[ii][j]);
    }

    if (MODE == 4) {
        static_assert(MODE != 4 || TN == 64, "MODE4 requires TN=64");
        int th = (int)bn / 12, h = (int)bn % 12;   // head-col = bn (TN=64)
        int sbase = ((int)bm * 128) & 2047;
        int b = ((int)bm * 128) >> 11;
        long bh_ = (long)b * 12 + h;
        if (th == 2) {
            // vT: RoPE into LDS [64 d][132 s] transpose tile (reuses staging
            // SMEM), then coalesced 256B dword rows. Replaces 2B/4KB-stride
            // scattered stores (64 txns/inst) with 1-txn coalesced stores.
            __syncthreads();
#pragma unroll
            for (int i = 0; i < 4; ++i) {
                int sl = wr * 64 + i * 16 + quad * 4;
#pragma unroll
                for (int j = 0; j < 2; ++j) {
                    int dh = j * 16 + l15;
                    bf16x4 p0, p1;
#pragma unroll
                    for (int r = 0; r < 4; ++r) {
                        int s = sbase + sl + r;
                        const float* cbp = cosb + s * 64;
                        const float* sbp = sinb + s * 64;
                        float a0f = acc[i][j][r], a1f = acc[i][j + 2][r];
                        p0[r] = f2bf_s(a0f * cbp[dh] - a1f * sbp[dh]);
                        p1[r] = f2bf_s(a1f * cbp[dh + 32] + a0f * sbp[dh + 32]);
                    }
                    *(bf16x4*)(SM + dh * 132 + sl) = p0;
                    *(bf16x4*)(SM + (dh + 32) * 132 + sl) = p1;
                }
            }
            __syncthreads();
            __hip_bfloat16* dst = vo + bh_ * 64 * 2048;
#pragma unroll
            for (int dd = 0; dd < 32; ++dd) {
                int d = wr * 32 + dd;
                unsigned pv = *(const unsigned*)(SM + d * 132 + lane * 2);
                *(unsigned*)(dst + (long)d * 2048 + sbase + lane * 2) = pv;
            }
            return;
        }
        // th 0/1: q (x0.125) / k, direct stores (16-lane 32B runs)
        float qs = (th == 0) ? 0.125f : 1.f;
        __hip_bfloat16* base = (th == 0) ? qo : ko;
#pragma unroll
        for (int i = 0; i < 4; ++i) {
#pragma unroll
            for (int r = 0; r < 4; ++r) {
                int s = sbase + wr * 64 + i * 16 + quad * 4 + r;
                const float* cbp = cosb + s * 64;
                const float* sbp = sinb + s * 64;
                __hip_bfloat16* d = base + (bh_ * 2048 + s) * 64;
#pragma unroll
                for (int j = 0; j < 2; ++j) {
                    int dh = j * 16 + l15;
                    float a0f = acc[i][j][r], a1f = acc[i][j + 2][r];
                    float o0 = a0f * cbp[dh] - a1f * sbp[dh];
                    float o1 = a1f * cbp[dh + 32] + a0f * sbp[dh + 32];
                    d[dh]      = __float2bfloat16(o0 * qs);
                    d[dh + 32] = __float2bfloat16(o1 * qs);
                }
            }
        }
        return;
    }

#pragma unroll
    for (int i = 0; i < 4; ++i) {
#pragma unroll
        for (int j = 0; j < 4; ++j) {
#pragma unroll
            for (int r = 0; r < 4; ++r) {
                int row = (int)bm * 128 + wr * 64 + i * 16 + quad * 4 + r;
                int col = (int)bn * TN + wc * 64 + j * 16 + l15;
                float v = acc[i][j][r];
                long idx = (long)row * N + col;
                if (MODE == 1) {
                    Cf[idx] = mods[(row >> 11) * 4608 + gateOff + col] * v + resid[idx];
                } else if (MODE == 2) {
                    Cb[idx] = __float2bfloat16(fast_gelu(v + bias[col]));
                } else {   // MODE 5: split-K partial
                    Cb[(long)blockIdx.z * M * N + idx] = __float2bfloat16(v);
                }
            }
        }
    }
}

extern "C" void kernel_launch(void* const* d_in, const int* in_sizes, int n_in,
                              void* d_out, int out_size, void* d_ws, size_t ws_size,
                              hipStream_t stream) {
    const float* x    = (const float*)d_in[0];
    const float* c    = (const float*)d_in[1];
    const float* cosb = (const float*)d_in[2];
    const float* sinb = (const float*)d_in[3];
    // d_in[4] = mask: unused, computed analytically
    const float* n1w  = (const float*)d_in[5];
    const float* qkvw = (const float*)d_in[6];
    const float* aow  = (const float*)d_in[7];
    const float* n2w  = (const float*)d_in[8];
    const float* w1   = (const float*)d_in[9];
    const float* b1   = (const float*)d_in[10];
    const float* w2   = (const float*)d_in[11];
    const float* b2   = (const float*)d_in[12];
    const float* alw  = (const float*)d_in[13];
    const float* alb  = (const float*)d_in[14];

    char* ws = (char*)d_ws;
    size_t off = 0;
    auto alloc = [&](size_t bytes) -> void* {
        void* p = ws + off;
        off += (bytes + 255) & ~(size_t)255;
        return p;
    };
    float*          mods = (float*)alloc(2 * 4608 * 4);
    __hip_bfloat16* hbuf = (__hip_bfloat16*)alloc((size_t)4096 * 768 * 2);
    __hip_bfloat16* qb   = (__hip_bfloat16*)alloc((size_t)24 * 2048 * 64 * 2);
    __hip_bfloat16* kb   = (__hip_bfloat16*)alloc((size_t)24 * 2048 * 64 * 2);
    __hip_bfloat16* vT   = (__hip_bfloat16*)alloc((size_t)24 * 64 * 2048 * 2);
    __hip_bfloat16* abuf = (__hip_bfloat16*)alloc((size_t)4096 * 768 * 2);
    float*          x2   = (float*)alloc((size_t)4096 * 768 * 4);
    __hip_bfloat16* h2   = (__hip_bfloat16*)alloc((size_t)4096 * 768 * 2);
    __hip_bfloat16* m1   = (__hip_bfloat16*)alloc((size_t)4096 * 3072 * 2);
    __hip_bfloat16* m2p  = (__hip_bfloat16*)alloc((size_t)4 * 4096 * 768 * 2);
    __hip_bfloat16* wq   = (__hip_bfloat16*)alloc((size_t)2304 * 768 * 2);
    __hip_bfloat16* wa   = (__hip_bfloat16*)alloc((size_t)768 * 768 * 2);
    __hip_bfloat16* w1b  = (__hip_bfloat16*)alloc((size_t)3072 * 768 * 2);
    __hip_bfloat16* w2b  = (__hip_bfloat16*)alloc((size_t)768 * 3072 * 2);

    // R23: vectorized convert (8/thread) -> 3456+36 blocks (was 27684)
    k_pre<<<3492, 256, 0, stream>>>(qkvw, wq, 2304 * 768, aow, wa, 768 * 768,
                                    w1, w1b, 3072 * 768, w2, w2b, 768 * 3072,
                                    c, alw, alb, mods);
    k_ln_mod<<<1024, 256, 0, stream>>>(x, n1w, mods, 0, 768, hbuf);
    // qkv GEMM + fused RoPE -> q, k, vT (TN=64 depth-2: 1152 blocks)
    k_gemm<4, 64><<<dim3(32, 36), 128, 0, stream>>>(hbuf, wq, nullptr, nullptr, nullptr, nullptr, 0,
                                                    nullptr, cosb, sinb, qb, kb, vT,
                                                    4096, 2304, 768, 768);
    k_attn<<<768, 256, 0, stream>>>(qb, kb, vT, abuf);
    k_gemm<1, 64><<<dim3(32, 12), 128, 0, stream>>>(abuf, wa, x2, nullptr, nullptr, mods, 1536,
                                                    x, nullptr, nullptr, nullptr, nullptr, nullptr,
                                                    4096, 768, 768, 768);
    k_ln_mod<<<1024, 256, 0, stream>>>(x2, n2w, mods, 2304, 3072, h2);
    // mlp1: 128x128 depth-1 (R9 config: L3-BW-bound, deeper pipeline hurts)
    k_gemm<2, 128><<<dim3(32, 24), 256, 0, stream>>>(h2, w1b, nullptr, m1, b1, nullptr, 0,
                                                     nullptr, nullptr, nullptr, nullptr, nullptr, nullptr,
                                                     4096, 3072, 768, 768);
    // mlp2: TN=128 + split-K=4, depth-1
    k_gemm<5, 128><<<dim3(32, 6, 4), 256, 0, stream>>>(m1, w2b, nullptr, m2p, nullptr, nullptr, 0,
                                                       nullptr, nullptr, nullptr, nullptr, nullptr, nullptr,
                                                       4096, 768, 768, 3072);
    k_red<<<1536, 256, 0, stream>>>(m2p, x2, mods, b2, (float*)d_out);
}